// Round 10
// baseline (308.052 us; speedup 1.0000x reference)
//
#include <hip/hip_runtime.h>
#include <math.h>

#define FD 128

typedef __attribute__((ext_vector_type(8))) _Float16 half8v;
typedef __attribute__((ext_vector_type(4))) _Float16 half4v;
typedef __attribute__((ext_vector_type(4))) float float4v;
typedef __attribute__((ext_vector_type(2))) float floatx2;

static __device__ __forceinline__ void dec8(unsigned int lo, unsigned int hi, float* f){
  floatx2 a = __builtin_amdgcn_cvt_pk_f32_fp8(lo, false);
  floatx2 b = __builtin_amdgcn_cvt_pk_f32_fp8(lo, true);
  floatx2 c = __builtin_amdgcn_cvt_pk_f32_fp8(hi, false);
  floatx2 d = __builtin_amdgcn_cvt_pk_f32_fp8(hi, true);
  f[0]=a[0]; f[1]=a[1]; f[2]=b[0]; f[3]=b[1];
  f[4]=c[0]; f[5]=c[1]; f[6]=d[0]; f[7]=d[1];
}

// ---------------- combined conversions: 8 weight mats -> fp16, x -> fp16 ----------------
__global__ void k_cvt_all(const float4* __restrict__ x4, half4v* __restrict__ Xh4, int n4x,
    const float* __restrict__ w0, const float* __restrict__ w1, const float* __restrict__ w2,
    const float* __restrict__ w3, const float* __restrict__ w4, const float* __restrict__ w5,
    const float* __restrict__ w6, const float* __restrict__ w7, _Float16* __restrict__ Wh){
  const int nw4 = 8 * FD * FD / 4;       // float4 units of weights
  int i = blockIdx.x * 256 + threadIdx.x, st = gridDim.x * 256;
  for (; i < nw4 + n4x; i += st){
    if (i < nw4){
      const int m = i >> 12;             // FD*FD/4 = 4096 float4 per matrix
      const int e = (i & 4095) << 2;
      const float* wm = (m==0)?w0:(m==1)?w1:(m==2)?w2:(m==3)?w3:(m==4)?w4:(m==5)?w5:(m==6)?w6:w7;
      float4 v = *(const float4*)(wm + e);
      half4v o;
      o[0]=(_Float16)v.x; o[1]=(_Float16)v.y; o[2]=(_Float16)v.z; o[3]=(_Float16)v.w;
      *(half4v*)(Wh + (size_t)m * FD * FD + e) = o;
    } else {
      const int j = i - nw4;
      float4 v = x4[j];
      half4v o;
      o[0]=(_Float16)v.x; o[1]=(_Float16)v.y; o[2]=(_Float16)v.z; o[3]=(_Float16)v.w;
      Xh4[j] = o;
    }
  }
}

// ---------------- CSR build (bucketed, low write-amplification) ----------------
__global__ __launch_bounds__(256) void k_bhist(const int* __restrict__ row, int E,
    int* __restrict__ bhist){
  __shared__ int h[256];
  h[threadIdx.x] = 0; __syncthreads();
  for (int i = blockIdx.x*256 + threadIdx.x; i < E; i += gridDim.x*256)
    atomicAdd(&h[row[i] >> 8], 1);
  __syncthreads();
  int v = h[threadIdx.x];
  if (v) atomicAdd(&bhist[threadIdx.x], v);
}

__global__ __launch_bounds__(256) void k_bscan(const int* __restrict__ bhist,
    int* __restrict__ bstart, int* __restrict__ bcursor, int E){
  __shared__ int sm[256];
  const int tid = threadIdx.x;
  int v = bhist[tid];
  sm[tid] = v; __syncthreads();
  for (int off = 1; off < 256; off <<= 1){
    int t = (tid >= off) ? sm[tid-off] : 0;
    __syncthreads();
    sm[tid] += t;
    __syncthreads();
  }
  bstart[tid] = sm[tid] - v;
  if (tid == 255) bstart[256] = E;
  bcursor[tid] = 0;
}

__global__ __launch_bounds__(256) void k_bscatter(const int* __restrict__ row,
    const int* __restrict__ col, int E, const int* __restrict__ bstart,
    int* __restrict__ bcursor, uint2* __restrict__ pairs){
  __shared__ int cnt[256];
  __shared__ int base[256];
  const int tid = threadIdx.x;
  const int per = (E + gridDim.x - 1) / gridDim.x;
  const int lo = blockIdx.x * per;
  const int hi = min(E, lo + per);
  cnt[tid] = 0; __syncthreads();
  for (int i = lo + tid; i < hi; i += 256)
    atomicAdd(&cnt[row[i] >> 8], 1);
  __syncthreads();
  base[tid] = cnt[tid] ? atomicAdd(&bcursor[tid], cnt[tid]) : 0;
  __syncthreads();
  cnt[tid] = 0; __syncthreads();
  for (int i = lo + tid; i < hi; i += 256){
    const int r = row[i];
    const int b = r >> 8;
    const int loc = atomicAdd(&cnt[b], 1);
    pairs[(size_t)bstart[b] + base[b] + loc] = make_uint2((unsigned)r, (unsigned)col[i]);
  }
}

__global__ __launch_bounds__(256) void k_bdeg(const uint2* __restrict__ pairs,
    const int* __restrict__ bstart, int N, int* __restrict__ deg){
  __shared__ int cnt[256];
  const int b = blockIdx.x, tid = threadIdx.x;
  cnt[tid] = 0; __syncthreads();
  const int lo = bstart[b], hi = bstart[b+1];
  for (int i = lo + tid; i < hi; i += 256)
    atomicAdd(&cnt[pairs[i].x & 255], 1);
  __syncthreads();
  const int r = (b << 8) + tid;
  if (r < N) deg[r] = cnt[tid];
}

__global__ __launch_bounds__(256) void k_bfill(const uint2* __restrict__ pairs,
    const int* __restrict__ bstart, const int* __restrict__ rowstart, int N,
    int* __restrict__ csrcol){
  __shared__ int base[256];
  __shared__ int cur[256];
  const int b = blockIdx.x, tid = threadIdx.x;
  const int r = (b << 8) + tid;
  base[tid] = (r < N) ? rowstart[r] : 0;
  cur[tid] = 0;
  __syncthreads();
  const int lo = bstart[b], hi = bstart[b+1];
  for (int i = lo + tid; i < hi; i += 256){
    uint2 p = pairs[i];
    const int rl = p.x & 255;
    const int loc = atomicAdd(&cur[rl], 1);
    csrcol[base[rl] + loc] = (int)p.y;
  }
}

// ---------------- deg scan -> rowstart ----------------
__global__ __launch_bounds__(256) void k_scan_blk(const int* __restrict__ in, int n,
    int* __restrict__ out, int* __restrict__ blksum){
  __shared__ int sm[256];
  const int tid = threadIdx.x;
  const int base = blockIdx.x * 1024;
  const int idx = base + tid * 4;
  int v0=0,v1=0,v2=0,v3=0;
  if (idx + 3 < n){ int4 t = *(const int4*)(in + idx); v0=t.x; v1=t.y; v2=t.z; v3=t.w; }
  else {
    if (idx   < n) v0 = in[idx];
    if (idx+1 < n) v1 = in[idx+1];
    if (idx+2 < n) v2 = in[idx+2];
    if (idx+3 < n) v3 = in[idx+3];
  }
  int s = v0+v1+v2+v3;
  sm[tid] = s; __syncthreads();
  for (int off = 1; off < 256; off <<= 1){
    int t = (tid >= off) ? sm[tid-off] : 0;
    __syncthreads();
    sm[tid] += t;
    __syncthreads();
  }
  int excl = sm[tid] - s;
  if (tid == 255) blksum[blockIdx.x] = sm[255];
  if (idx   < n) out[idx]   = excl;
  if (idx+1 < n) out[idx+1] = excl + v0;
  if (idx+2 < n) out[idx+2] = excl + v0 + v1;
  if (idx+3 < n) out[idx+3] = excl + v0 + v1 + v2;
}

__global__ __launch_bounds__(256) void k_scan_part(const int* __restrict__ blksum, int nblk,
    int* __restrict__ blkoff){
  __shared__ int sm[256];
  const int tid = threadIdx.x;
  int v = (tid < nblk) ? blksum[tid] : 0;
  sm[tid] = v; __syncthreads();
  for (int off = 1; off < 256; off <<= 1){
    int t = (tid >= off) ? sm[tid-off] : 0;
    __syncthreads();
    sm[tid] += t;
    __syncthreads();
  }
  if (tid < nblk) blkoff[tid] = sm[tid] - v;
}

__global__ __launch_bounds__(256) void k_scan_add(int* __restrict__ out, int n,
    const int* __restrict__ blkoff, int E){
  int i = blockIdx.x * 256 + threadIdx.x;
  if (i < n) out[i] += blkoff[i >> 10];
  if (i == 0) out[n] = E;
}

// ---------------- LDS-staged MFMA f16 GEMM (1..3 outputs) ----------------
// OMODE: 0 = all outputs fp16; 1 = output0 fp32; 2 = QKV (out0 fp16, out1/out2 fp8 e4m3)
template<int NOUT, int ACT, int OMODE>
__global__ __launch_bounds__(256) void k_gemm_lds(const _Float16* __restrict__ X, int ldx,
    const _Float16* __restrict__ W,
    const float* __restrict__ b0, void* __restrict__ Y0,
    const float* __restrict__ b1, void* __restrict__ Y1,
    const float* __restrict__ b2, void* __restrict__ Y2,
    int ldy, int nrows)
{
  __shared__ _Float16 sW[FD * FD];    // 32 KB
  const int tid  = threadIdx.x;
  const int wid  = tid >> 6;
  const int lane = tid & 63;
  const int l4 = lane & 15;
  const int kg = lane >> 4;
  const int r0 = blockIdx.x * 64 + wid * 16;

  int rA = r0 + l4; if (rA > nrows - 1) rA = nrows - 1;
  half8v xf[4];
  #pragma unroll
  for (int ks = 0; ks < 4; ks++)
    xf[ks] = *(const half8v*)(X + (size_t)rA * ldx + ks*32 + kg*8);

  for (int o = 0; o < NOUT; o++){
    if (o) __syncthreads();
    const _Float16* Wo = W + (size_t)o * FD * FD;
    #pragma unroll
    for (int j = 0; j < 8; j++){
      const int b = j*4096 + tid*16;
      const int row = b >> 8, cb = b & 255;
      half8v v = *(const half8v*)((const char*)Wo + b);
      *(half8v*)((char*)sW + ((row*256 + (cb ^ ((row & 7) << 4))))) = v;
    }
    __syncthreads();

    float4v acc[8];
    #pragma unroll
    for (int t = 0; t < 8; t++)
      #pragma unroll
      for (int i = 0; i < 4; i++) acc[t][i] = 0.f;

    #pragma unroll
    for (int t = 0; t < 8; t++){
      const int row = t*16 + l4;
      const int sw = (row & 7) << 4;
      #pragma unroll
      for (int ks = 0; ks < 4; ks++){
        half8v wf = *(const half8v*)((const char*)sW + (row*256 + ((ks*64 + kg*16) ^ sw)));
        acc[t] = __builtin_amdgcn_mfma_f32_16x16x32_f16(wf, xf[ks], acc[t], 0, 0, 0);
      }
    }

    const float* bo = (o == 0) ? b0 : (o == 1) ? b1 : b2;
    void* Yo = (o == 0) ? Y0 : (o == 1) ? Y1 : Y2;
    const int r = r0 + l4;
    if (r < nrows){
      #pragma unroll
      for (int t = 0; t < 8; t++){
        const int c = t*16 + kg*4;
        const float4 bb = *(const float4*)(bo + c);
        float v0 = acc[t][0] + bb.x, v1 = acc[t][1] + bb.y;
        float v2 = acc[t][2] + bb.z, v3 = acc[t][3] + bb.w;
        if (ACT){ v0=fmaxf(v0,0.f); v1=fmaxf(v1,0.f); v2=fmaxf(v2,0.f); v3=fmaxf(v3,0.f); }
        if (OMODE == 1 && o == 0){
          *(float4*)((float*)Yo + (size_t)r * ldy + c) = make_float4(v0, v1, v2, v3);
        } else if (OMODE == 2 && o > 0){
          unsigned int w01 = (unsigned int)__builtin_amdgcn_cvt_pk_fp8_f32(v0, v1, 0, false);
          unsigned int w   = (unsigned int)__builtin_amdgcn_cvt_pk_fp8_f32(v2, v3, (int)w01, true);
          *(unsigned int*)((unsigned char*)Yo + (size_t)r * FD + c) = w;
        } else {
          half4v hv;
          hv[0]=(_Float16)v0; hv[1]=(_Float16)v1; hv[2]=(_Float16)v2; hv[3]=(_Float16)v3;
          *(half4v*)((_Float16*)Yo + (size_t)r * ldy + c) = hv;
        }
      }
    }
  }
}

// ---------------- edge passes: quarter-wave (16 lanes)/node, 8 dims/lane, 8 edges/iter ----
#define SC 0.08838834764831845f

#define RED16(d) \
  d += __shfl_xor(d, 1); d += __shfl_xor(d, 2); d += __shfl_xor(d, 4); d += __shfl_xor(d, 8);

#define SEL8(sv, d, l4) \
  sv = d[0]; \
  sv = (l4==1)?d[1]:sv; sv = (l4==2)?d[2]:sv; sv = (l4==3)?d[3]:sv; \
  sv = (l4==4)?d[4]:sv; sv = (l4==5)?d[5]:sv; sv = (l4==6)?d[6]:sv; sv = (l4==7)?d[7]:sv;

// scores1 (Qh . K8) fused with segment-mean of Xh -> SMh (fp16 strided)
__global__ __launch_bounds__(256) void k_passA(const _Float16* __restrict__ Qh,
    const unsigned char* __restrict__ K8, const _Float16* __restrict__ Xh,
    const int* __restrict__ rowstart, const int* __restrict__ csrcol,
    float* __restrict__ scores, _Float16* __restrict__ SMh, int ldsm, int nnodes)
{
  const int tid = threadIdx.x;
  const int n = blockIdx.x * 16 + (tid >> 4);
  if (n >= nnodes) return;
  const int l4 = tid & 15;
  const half8v qv = *(const half8v*)(Qh + (size_t)n * FD + 8*l4);
  float qf[8];
  #pragma unroll
  for (int i = 0; i < 8; i++) qf[i] = (float)qv[i];
  float sx[8];
  #pragma unroll
  for (int i = 0; i < 8; i++) sx[i] = 0.f;
  const int p0 = rowstart[n], p1 = rowstart[n+1];
  const int last = p1 - 1;
  for (int p = p0; p < p1; p += 8){
    int cc[8]; float mk[8];
    #pragma unroll
    for (int j = 0; j < 8; j++){
      const int idx = p + j;
      cc[j] = csrcol[idx < p1 ? idx : last];
      mk[j] = idx < p1 ? 1.f : 0.f;
    }
    uint2 ku[8]; half8v xv[8];
    #pragma unroll
    for (int j = 0; j < 8; j++){
      ku[j] = *(const uint2*)(K8 + (size_t)cc[j]*FD + 8*l4);
      xv[j] = *(const half8v*)(Xh + (size_t)cc[j]*FD + 8*l4);
    }
    float d[8];
    #pragma unroll
    for (int j = 0; j < 8; j++){
      float kf[8];
      dec8(ku[j].x, ku[j].y, kf);
      float t = 0.f;
      #pragma unroll
      for (int i = 0; i < 8; i++) t += qf[i] * kf[i];
      d[j] = t;
      #pragma unroll
      for (int i = 0; i < 8; i++) sx[i] += mk[j] * (float)xv[j][i];
    }
    #pragma unroll
    for (int j = 0; j < 8; j++){ RED16(d[j]) }
    float sv;
    SEL8(sv, d, l4)
    if (l4 < 8 && p + l4 < p1) scores[p + l4] = sv * SC;
  }
  int dg = p1 - p0; if (dg < 1) dg = 1;
  const float inv = 1.f / (float)dg;
  half8v o;
  #pragma unroll
  for (int i = 0; i < 8; i++) o[i] = (_Float16)(sx[i]*inv);
  *(half8v*)(SMh + (size_t)n * ldsm + 8*l4) = o;
}

// scores (layer 2): Qh fp16, K8 fp8
__global__ __launch_bounds__(256) void k_scores2(const _Float16* __restrict__ Qh,
    const unsigned char* __restrict__ K8,
    const int* __restrict__ rowstart, const int* __restrict__ csrcol,
    float* __restrict__ scores, int nnodes)
{
  const int tid = threadIdx.x;
  const int n = blockIdx.x * 16 + (tid >> 4);
  if (n >= nnodes) return;
  const int l4 = tid & 15;
  const int p0 = rowstart[n], p1 = rowstart[n+1];
  if (p0 >= p1) return;
  const half8v qv = *(const half8v*)(Qh + (size_t)n * FD + 8*l4);
  float qf[8];
  #pragma unroll
  for (int i = 0; i < 8; i++) qf[i] = (float)qv[i];
  const int last = p1 - 1;
  for (int p = p0; p < p1; p += 8){
    int cc[8];
    #pragma unroll
    for (int j = 0; j < 8; j++){
      const int idx = p + j;
      cc[j] = csrcol[idx < p1 ? idx : last];
    }
    uint2 ku[8];
    #pragma unroll
    for (int j = 0; j < 8; j++)
      ku[j] = *(const uint2*)(K8 + (size_t)cc[j]*FD + 8*l4);
    float d[8];
    #pragma unroll
    for (int j = 0; j < 8; j++){
      float kf[8];
      dec8(ku[j].x, ku[j].y, kf);
      float t = 0.f;
      #pragma unroll
      for (int i = 0; i < 8; i++) t += qf[i] * kf[i];
      d[j] = t;
    }
    #pragma unroll
    for (int j = 0; j < 8; j++){ RED16(d[j]) }
    float sv;
    SEL8(sv, d, l4)
    if (l4 < 8 && p + l4 < p1) scores[p + l4] = sv * SC;
  }
}

// message1 (alpha-weighted V8, ELU -> Ah fp16) fused with segment-mean of Sh -> Bh
__global__ __launch_bounds__(256) void k_passB(const unsigned char* __restrict__ V8,
    const _Float16* __restrict__ Sh,
    const float* __restrict__ sc, const float* __restrict__ Mp, const float* __restrict__ Ip,
    const int* __restrict__ rowstart, const int* __restrict__ csrcol,
    _Float16* __restrict__ Ah, _Float16* __restrict__ Bh, int ldb, int nnodes)
{
  const int tid = threadIdx.x;
  const int n = blockIdx.x * 16 + (tid >> 4);
  if (n >= nnodes) return;
  const int l4 = tid & 15;
  const float M = Mp[0], inv = Ip[0];
  float av[8], sv[8];
  #pragma unroll
  for (int i = 0; i < 8; i++){ av[i] = 0.f; sv[i] = 0.f; }
  const int p0 = rowstart[n], p1 = rowstart[n+1];
  const int last = p1 - 1;
  for (int p = p0; p < p1; p += 8){
    int cc[8]; float aa[8], mk[8];
    #pragma unroll
    for (int j = 0; j < 8; j++){
      const int idx = p + j;
      const int eff = idx < p1 ? idx : last;
      cc[j] = csrcol[eff];
      aa[j] = sc[eff];
      mk[j] = idx < p1 ? 1.f : 0.f;
    }
    uint2 vu[8]; half8v ss[8];
    #pragma unroll
    for (int j = 0; j < 8; j++){
      vu[j] = *(const uint2*)(V8 + (size_t)cc[j]*FD + 8*l4);
      ss[j] = *(const half8v*)(Sh + (size_t)cc[j]*FD + 8*l4);
    }
    #pragma unroll
    for (int j = 0; j < 8; j++){
      const float a = mk[j] * __expf(aa[j] - M);
      float vf[8];
      dec8(vu[j].x, vu[j].y, vf);
      #pragma unroll
      for (int i = 0; i < 8; i++){
        av[i] += a * vf[i];
        sv[i] += mk[j] * (float)ss[j][i];
      }
    }
  }
  #pragma unroll
  for (int i = 0; i < 8; i++){
    float v = av[i] * inv;
    av[i] = v > 0.f ? v : expm1f(v);
  }
  half8v oa;
  #pragma unroll
  for (int i = 0; i < 8; i++) oa[i] = (_Float16)av[i];
  *(half8v*)(Ah + (size_t)n * FD + 8*l4) = oa;
  int dg = p1 - p0; if (dg < 1) dg = 1;
  const float invd = 1.f / (float)dg;
  half8v ob;
  #pragma unroll
  for (int i = 0; i < 8; i++) ob[i] = (_Float16)(sv[i]*invd);
  *(half8v*)(Bh + (size_t)n * ldb + 8*l4) = ob;
}

// message2 -> out (fp32), V8 fp8
__global__ __launch_bounds__(256) void k_message2(const unsigned char* __restrict__ V8,
    const float* __restrict__ sc, const float* __restrict__ Mp, const float* __restrict__ Ip,
    const int* __restrict__ rowstart, const int* __restrict__ csrcol,
    float* __restrict__ out, int ldo, int nnodes)
{
  const int tid = threadIdx.x;
  const int n = blockIdx.x * 16 + (tid >> 4);
  if (n >= nnodes) return;
  const int l4 = tid & 15;
  const float M = Mp[0], inv = Ip[0];
  float av[8];
  #pragma unroll
  for (int i = 0; i < 8; i++) av[i] = 0.f;
  const int p0 = rowstart[n], p1 = rowstart[n+1];
  const int last = p1 - 1;
  for (int p = p0; p < p1; p += 8){
    int cc[8]; float aa[8], mk[8];
    #pragma unroll
    for (int j = 0; j < 8; j++){
      const int idx = p + j;
      const int eff = idx < p1 ? idx : last;
      cc[j] = csrcol[eff];
      aa[j] = sc[eff];
      mk[j] = idx < p1 ? 1.f : 0.f;
    }
    uint2 vu[8];
    #pragma unroll
    for (int j = 0; j < 8; j++)
      vu[j] = *(const uint2*)(V8 + (size_t)cc[j]*FD + 8*l4);
    #pragma unroll
    for (int j = 0; j < 8; j++){
      const float a = mk[j] * __expf(aa[j] - M);
      float vf[8];
      dec8(vu[j].x, vu[j].y, vf);
      #pragma unroll
      for (int i = 0; i < 8; i++) av[i] += a * vf[i];
    }
  }
  float* op = out + (size_t)n * ldo + 8*l4;
  *(float4*)(op    ) = make_float4(av[0]*inv, av[1]*inv, av[2]*inv, av[3]*inv);
  *(float4*)(op + 4) = make_float4(av[4]*inv, av[5]*inv, av[6]*inv, av[7]*inv);
}

// ---------------- fused online softmax reductions ----------------
__global__ __launch_bounds__(256) void k_sm_partial(const float* __restrict__ s, int n,
    float* __restrict__ pm, float* __restrict__ ps){
  __shared__ float sm_m[256], sm_s[256];
  const int tid = threadIdx.x;
  float m = -3.402823466e38f, sum = 0.f;
  const int n4 = n >> 2;
  const float4* s4 = (const float4*)s;
  for (int i = blockIdx.x * 256 + tid; i < n4; i += gridDim.x * 256){
    float4 q = s4[i];
    float vv[4] = {q.x, q.y, q.z, q.w};
    #pragma unroll
    for (int j = 0; j < 4; j++){
      float v = vv[j];
      if (v <= m) sum += __expf(v - m);
      else { sum = sum * __expf(m - v) + 1.f; m = v; }
    }
  }
  if (blockIdx.x == 0 && tid < (n - (n4 << 2))){
    float v = s[(n4 << 2) + tid];
    if (v <= m) sum += __expf(v - m);
    else { sum = sum * __expf(m - v) + 1.f; m = v; }
  }
  sm_m[tid] = m; sm_s[tid] = sum; __syncthreads();
  for (int off = 128; off > 0; off >>= 1){
    if (tid < off){
      float m2 = sm_m[tid + off], s2 = sm_s[tid + off];
      float m1 = sm_m[tid], s1 = sm_s[tid];
      float Mx = fmaxf(m1, m2);
      sm_m[tid] = Mx;
      sm_s[tid] = s1 * __expf(m1 - Mx) + s2 * __expf(m2 - Mx);
    }
    __syncthreads();
  }
  if (tid == 0){ pm[blockIdx.x] = sm_m[0]; ps[blockIdx.x] = sm_s[0]; }
}

__global__ __launch_bounds__(256) void k_sm_final(const float* __restrict__ pm, const float* __restrict__ ps,
    int n, float* __restrict__ Mout, float* __restrict__ Iout){
  __shared__ float sm_m[256], sm_s[256];
  const int tid = threadIdx.x;
  float m = -3.402823466e38f, sum = 0.f;
  for (int i = tid; i < n; i += 256){
    float m2 = pm[i], s2 = ps[i];
    float Mx = fmaxf(m, m2);
    sum = sum * __expf(m - Mx) + s2 * __expf(m2 - Mx);
    m = Mx;
  }
  sm_m[tid] = m; sm_s[tid] = sum; __syncthreads();
  for (int off = 128; off > 0; off >>= 1){
    if (tid < off){
      float m2 = sm_m[tid + off], s2 = sm_s[tid + off];
      float m1 = sm_m[tid], s1 = sm_s[tid];
      float Mx = fmaxf(m1, m2);
      sm_m[tid] = Mx;
      sm_s[tid] = s1 * __expf(m1 - Mx) + s2 * __expf(m2 - Mx);
    }
    __syncthreads();
  }
  if (tid == 0){ Mout[0] = sm_m[0]; Iout[0] = 1.f / sm_s[0]; }
}

extern "C" void kernel_launch(void* const* d_in, const int* in_sizes, int n_in,
                              void* d_out, int out_size, void* d_ws, size_t ws_size,
                              hipStream_t stream)
{
  const float* x   = (const float*)d_in[0];
  const int*   ei  = (const int*)d_in[1];
  const float* Wq1 = (const float*)d_in[2];  const float* bq1 = (const float*)d_in[3];
  const float* Wk1 = (const float*)d_in[4];  const float* bk1 = (const float*)d_in[5];
  const float* Wv1 = (const float*)d_in[6];  const float* bv1 = (const float*)d_in[7];
  const float* Wq2 = (const float*)d_in[8];  const float* bq2 = (const float*)d_in[9];
  const float* Wk2 = (const float*)d_in[10]; const float* bk2 = (const float*)d_in[11];
  const float* Wv2 = (const float*)d_in[12]; const float* bv2 = (const float*)d_in[13];
  const float* Ws1 = (const float*)d_in[14]; const float* bs1 = (const float*)d_in[15];
  const float* Ws2 = (const float*)d_in[16]; const float* bs2 = (const float*)d_in[17];

  const int N = in_sizes[0] / FD;
  const int E = in_sizes[1] / 2;
  const int* row = ei;
  const int* col = ei + E;
  float* out = (float*)d_out;

  char* ws = (char*)d_ws;
  size_t off = 0;
  auto alloc = [&](size_t bytes) -> void* {
    void* p = ws + off;
    off += (bytes + 255) & ~(size_t)255;
    return p;
  };
  int* deg      = (int*)alloc((size_t)N * 4);
  int* rowstart = (int*)alloc((size_t)(N + 1) * 4);
  int* csrcol   = (int*)alloc((size_t)E * 4);
  uint2* pairs  = (uint2*)alloc((size_t)E * 8);
  int* bhist    = (int*)alloc(1024);
  int* bstart   = (int*)alloc(1056);
  int* bcursor  = (int*)alloc(1024);
  float* scores = (float*)alloc((size_t)E * 4);
  int* blksum   = (int*)alloc(1024);
  int* blkoff   = (int*)alloc(1024);
  float* pm     = (float*)alloc(1024);
  float* ps     = (float*)alloc(1024);
  float* Mv     = (float*)alloc(256);
  float* Iv     = (float*)alloc(256);
  _Float16* Xh = (_Float16*)alloc((size_t)N * FD * 2);   // x fp16; aliased as Sh after passA
  _Float16* Qh = (_Float16*)alloc((size_t)N * FD * 2);
  unsigned char* K8 = (unsigned char*)alloc((size_t)N * FD);
  unsigned char* V8 = (unsigned char*)alloc((size_t)N * FD);
  _Float16* Ah = (_Float16*)alloc((size_t)N * FD * 2);
  _Float16* Wh = (_Float16*)alloc((size_t)8 * FD * FD * 2);
  _Float16* Sh = Xh;                 // s1: Xh dead after passA
  _Float16* SMBh = (_Float16*)out;   // seg-mean scratch inside out cols[0,128) bytes, ld 512 halfs
  (void)ws_size; (void)n_in; (void)out_size;

  hipMemsetAsync(bhist, 0, 1024, stream);

  // conversions (one kernel: 8 weight matrices + x)
  k_cvt_all<<<2048, 256, 0, stream>>>((const float4*)x, (half4v*)Xh, N * FD / 4,
      Wq1, Wk1, Wv1, Wq2, Wk2, Wv2, Ws1, Ws2, Wh);

  // ---- bucketed CSR build ----
  const int nbuckets = (N + 255) >> 8;
  const int nblk = (N + 1023) / 1024;
  k_bhist<<<1024, 256, 0, stream>>>(row, E, bhist);
  k_bscan<<<1, 256, 0, stream>>>(bhist, bstart, bcursor, E);
  k_bscatter<<<256, 256, 0, stream>>>(row, col, E, bstart, bcursor, pairs);
  k_bdeg<<<nbuckets, 256, 0, stream>>>(pairs, bstart, N, deg);
  k_scan_blk<<<nblk, 256, 0, stream>>>(deg, N, rowstart, blksum);
  k_scan_part<<<1, 256, 0, stream>>>(blksum, nblk, blkoff);
  k_scan_add<<<(N + 255)/256, 256, 0, stream>>>(rowstart, N, blkoff, E);
  k_bfill<<<nbuckets, 256, 0, stream>>>(pairs, bstart, rowstart, N, csrcol);

  const int gb = (N + 63) / 64;
  const int nb = (N + 15) / 16;   // quarter-wave edge kernels: 16 nodes/block
  const int rb = 256;

  // ---- layer-1 QKV (LDS-staged MFMA f16; Q fp16, K/V fp8) ----
  k_gemm_lds<3,0,2><<<gb, 256, 0, stream>>>(Xh, FD, Wh + 0*FD*FD,
      bq1, Qh, bk1, K8, bv1, V8, FD, N);

  // ---- fused: scores1 + seg_mean(Xh) -> SMBh (fp16 in out, ld 512) ----
  k_passA<<<nb, 256, 0, stream>>>(Qh, K8, Xh, rowstart, csrcol, scores, SMBh, 512, N);

  k_sm_partial<<<rb, 256, 0, stream>>>(scores, E, pm, ps);
  k_sm_final<<<1, 256, 0, stream>>>(pm, ps, rb, Mv, Iv);

  // s1 = relu(SMBh @ Ws1^T + bs1) -> Sh (fp16 packed; overwrites dead Xh)
  k_gemm_lds<1,1,0><<<gb, 256, 0, stream>>>(SMBh, 512, Wh + 6*FD*FD,
      bs1, Sh, nullptr, nullptr, nullptr, nullptr, FD, N);

  // ---- fused: message1+ELU -> Ah; seg_mean(s1) -> Bh (= SMBh region, SM dead) ----
  k_passB<<<nb, 256, 0, stream>>>(V8, Sh, scores, Mv, Iv, rowstart, csrcol, Ah, SMBh, 512, N);

  // ss_out = relu(Bh @ Ws2^T + bs2) -> out cols [128,256) fp32
  k_gemm_lds<1,1,1><<<gb, 256, 0, stream>>>(SMBh, 512, Wh + 7*FD*FD,
      bs2, out + FD, nullptr, nullptr, nullptr, nullptr, 2*FD, N);

  // ---- layer-2 QKV (overwrites Qh/K8/V8 after passB consumed V8) ----
  k_gemm_lds<3,0,2><<<gb, 256, 0, stream>>>(Ah, FD, Wh + 3*FD*FD,
      bq2, Qh, bk2, K8, bv2, V8, FD, N);
  k_scores2<<<nb, 256, 0, stream>>>(Qh, K8, rowstart, csrcol, scores, N);

  k_sm_partial<<<rb, 256, 0, stream>>>(scores, E, pm, ps);
  k_sm_final<<<1, 256, 0, stream>>>(pm, ps, rb, Mv, Iv);

  // message2 -> out cols [0,128) fp32
  k_message2<<<nb, 256, 0, stream>>>(V8, scores, Mv, Iv, rowstart, csrcol, out, 2*FD, N);
}

// Round 11
// 301.483 us; speedup vs baseline: 1.0218x; 1.0218x over previous
//
#include <hip/hip_runtime.h>
#include <math.h>

#define FD 128

typedef __attribute__((ext_vector_type(8))) _Float16 half8v;
typedef __attribute__((ext_vector_type(4))) _Float16 half4v;
typedef __attribute__((ext_vector_type(4))) float float4v;
typedef __attribute__((ext_vector_type(2))) float floatx2;

static __device__ __forceinline__ void dec8(unsigned int lo, unsigned int hi, float* f){
  floatx2 a = __builtin_amdgcn_cvt_pk_f32_fp8(lo, false);
  floatx2 b = __builtin_amdgcn_cvt_pk_f32_fp8(lo, true);
  floatx2 c = __builtin_amdgcn_cvt_pk_f32_fp8(hi, false);
  floatx2 d = __builtin_amdgcn_cvt_pk_f32_fp8(hi, true);
  f[0]=a[0]; f[1]=a[1]; f[2]=b[0]; f[3]=b[1];
  f[4]=c[0]; f[5]=c[1]; f[6]=d[0]; f[7]=d[1];
}

// online-softmax lane update
#define OSM_PUSH(om, os, v) \
  { if ((v) <= om) os += __expf((v) - om); \
    else { os = os * __expf(om - (v)) + 1.f; om = (v); } }

// ---------------- combined conversions: 8 weight mats -> fp16, x -> fp16 ----------------
__global__ void k_cvt_all(const float4* __restrict__ x4, half4v* __restrict__ Xh4, int n4x,
    const float* __restrict__ w0, const float* __restrict__ w1, const float* __restrict__ w2,
    const float* __restrict__ w3, const float* __restrict__ w4, const float* __restrict__ w5,
    const float* __restrict__ w6, const float* __restrict__ w7, _Float16* __restrict__ Wh){
  const int nw4 = 8 * FD * FD / 4;
  int i = blockIdx.x * 256 + threadIdx.x, st = gridDim.x * 256;
  for (; i < nw4 + n4x; i += st){
    if (i < nw4){
      const int m = i >> 12;
      const int e = (i & 4095) << 2;
      const float* wm = (m==0)?w0:(m==1)?w1:(m==2)?w2:(m==3)?w3:(m==4)?w4:(m==5)?w5:(m==6)?w6:w7;
      float4 v = *(const float4*)(wm + e);
      half4v o;
      o[0]=(_Float16)v.x; o[1]=(_Float16)v.y; o[2]=(_Float16)v.z; o[3]=(_Float16)v.w;
      *(half4v*)(Wh + (size_t)m * FD * FD + e) = o;
    } else {
      const int j = i - nw4;
      float4 v = x4[j];
      half4v o;
      o[0]=(_Float16)v.x; o[1]=(_Float16)v.y; o[2]=(_Float16)v.z; o[3]=(_Float16)v.w;
      Xh4[j] = o;
    }
  }
}

// ---------------- CSR build (bucketed, low write-amplification) ----------------
__global__ __launch_bounds__(256) void k_bhist(const int* __restrict__ row, int E,
    int* __restrict__ bhist){
  __shared__ int h[256];
  h[threadIdx.x] = 0; __syncthreads();
  for (int i = blockIdx.x*256 + threadIdx.x; i < E; i += gridDim.x*256)
    atomicAdd(&h[row[i] >> 8], 1);
  __syncthreads();
  int v = h[threadIdx.x];
  if (v) atomicAdd(&bhist[threadIdx.x], v);
}

__global__ __launch_bounds__(256) void k_bscan(const int* __restrict__ bhist,
    int* __restrict__ bstart, int* __restrict__ bcursor, int E){
  __shared__ int sm[256];
  const int tid = threadIdx.x;
  int v = bhist[tid];
  sm[tid] = v; __syncthreads();
  for (int off = 1; off < 256; off <<= 1){
    int t = (tid >= off) ? sm[tid-off] : 0;
    __syncthreads();
    sm[tid] += t;
    __syncthreads();
  }
  bstart[tid] = sm[tid] - v;
  if (tid == 255) bstart[256] = E;
  bcursor[tid] = 0;
}

__global__ __launch_bounds__(256) void k_bscatter(const int* __restrict__ row,
    const int* __restrict__ col, int E, const int* __restrict__ bstart,
    int* __restrict__ bcursor, uint2* __restrict__ pairs){
  __shared__ int cnt[256];
  __shared__ int base[256];
  const int tid = threadIdx.x;
  const int per = (E + gridDim.x - 1) / gridDim.x;
  const int lo = blockIdx.x * per;
  const int hi = min(E, lo + per);
  cnt[tid] = 0; __syncthreads();
  for (int i = lo + tid; i < hi; i += 256)
    atomicAdd(&cnt[row[i] >> 8], 1);
  __syncthreads();
  base[tid] = cnt[tid] ? atomicAdd(&bcursor[tid], cnt[tid]) : 0;
  __syncthreads();
  cnt[tid] = 0; __syncthreads();
  for (int i = lo + tid; i < hi; i += 256){
    const int r = row[i];
    const int b = r >> 8;
    const int loc = atomicAdd(&cnt[b], 1);
    pairs[(size_t)bstart[b] + base[b] + loc] = make_uint2((unsigned)r, (unsigned)col[i]);
  }
}

__global__ __launch_bounds__(256) void k_bdeg(const uint2* __restrict__ pairs,
    const int* __restrict__ bstart, int N, int* __restrict__ deg){
  __shared__ int cnt[256];
  const int b = blockIdx.x, tid = threadIdx.x;
  cnt[tid] = 0; __syncthreads();
  const int lo = bstart[b], hi = bstart[b+1];
  for (int i = lo + tid; i < hi; i += 256)
    atomicAdd(&cnt[pairs[i].x & 255], 1);
  __syncthreads();
  const int r = (b << 8) + tid;
  if (r < N) deg[r] = cnt[tid];
}

__global__ __launch_bounds__(256) void k_bfill(const uint2* __restrict__ pairs,
    const int* __restrict__ bstart, const int* __restrict__ rowstart, int N,
    int* __restrict__ csrcol){
  __shared__ int base[256];
  __shared__ int cur[256];
  const int b = blockIdx.x, tid = threadIdx.x;
  const int r = (b << 8) + tid;
  base[tid] = (r < N) ? rowstart[r] : 0;
  cur[tid] = 0;
  __syncthreads();
  const int lo = bstart[b], hi = bstart[b+1];
  for (int i = lo + tid; i < hi; i += 256){
    uint2 p = pairs[i];
    const int rl = p.x & 255;
    const int loc = atomicAdd(&cur[rl], 1);
    csrcol[base[rl] + loc] = (int)p.y;
  }
}

// ---------------- deg scan -> rowstart ----------------
__global__ __launch_bounds__(256) void k_scan_blk(const int* __restrict__ in, int n,
    int* __restrict__ out, int* __restrict__ blksum){
  __shared__ int sm[256];
  const int tid = threadIdx.x;
  const int base = blockIdx.x * 1024;
  const int idx = base + tid * 4;
  int v0=0,v1=0,v2=0,v3=0;
  if (idx + 3 < n){ int4 t = *(const int4*)(in + idx); v0=t.x; v1=t.y; v2=t.z; v3=t.w; }
  else {
    if (idx   < n) v0 = in[idx];
    if (idx+1 < n) v1 = in[idx+1];
    if (idx+2 < n) v2 = in[idx+2];
    if (idx+3 < n) v3 = in[idx+3];
  }
  int s = v0+v1+v2+v3;
  sm[tid] = s; __syncthreads();
  for (int off = 1; off < 256; off <<= 1){
    int t = (tid >= off) ? sm[tid-off] : 0;
    __syncthreads();
    sm[tid] += t;
    __syncthreads();
  }
  int excl = sm[tid] - s;
  if (tid == 255) blksum[blockIdx.x] = sm[255];
  if (idx   < n) out[idx]   = excl;
  if (idx+1 < n) out[idx+1] = excl + v0;
  if (idx+2 < n) out[idx+2] = excl + v0 + v1;
  if (idx+3 < n) out[idx+3] = excl + v0 + v1 + v2;
}

__global__ __launch_bounds__(256) void k_scan_part(const int* __restrict__ blksum, int nblk,
    int* __restrict__ blkoff){
  __shared__ int sm[256];
  const int tid = threadIdx.x;
  int v = (tid < nblk) ? blksum[tid] : 0;
  sm[tid] = v; __syncthreads();
  for (int off = 1; off < 256; off <<= 1){
    int t = (tid >= off) ? sm[tid-off] : 0;
    __syncthreads();
    sm[tid] += t;
    __syncthreads();
  }
  if (tid < nblk) blkoff[tid] = sm[tid] - v;
}

__global__ __launch_bounds__(256) void k_scan_add(int* __restrict__ out, int n,
    const int* __restrict__ blkoff, int E){
  int i = blockIdx.x * 256 + threadIdx.x;
  if (i < n) out[i] += blkoff[i >> 10];
  if (i == 0) out[n] = E;
}

// ---------------- LDS-staged MFMA f16 GEMM (1..3 outputs) ----------------
// OMODE: 0 = all outputs fp16; 1 = output0 fp32; 2 = QKV (out0 fp16, out1/out2 fp8 e4m3)
template<int NOUT, int ACT, int OMODE>
__global__ __launch_bounds__(256) void k_gemm_lds(const _Float16* __restrict__ X, int ldx,
    const _Float16* __restrict__ W,
    const float* __restrict__ b0, void* __restrict__ Y0,
    const float* __restrict__ b1, void* __restrict__ Y1,
    const float* __restrict__ b2, void* __restrict__ Y2,
    int ldy, int nrows)
{
  __shared__ _Float16 sW[FD * FD];    // 32 KB
  const int tid  = threadIdx.x;
  const int wid  = tid >> 6;
  const int lane = tid & 63;
  const int l4 = lane & 15;
  const int kg = lane >> 4;
  const int r0 = blockIdx.x * 64 + wid * 16;

  int rA = r0 + l4; if (rA > nrows - 1) rA = nrows - 1;
  half8v xf[4];
  #pragma unroll
  for (int ks = 0; ks < 4; ks++)
    xf[ks] = *(const half8v*)(X + (size_t)rA * ldx + ks*32 + kg*8);

  for (int o = 0; o < NOUT; o++){
    if (o) __syncthreads();
    const _Float16* Wo = W + (size_t)o * FD * FD;
    #pragma unroll
    for (int j = 0; j < 8; j++){
      const int b = j*4096 + tid*16;
      const int row = b >> 8, cb = b & 255;
      half8v v = *(const half8v*)((const char*)Wo + b);
      *(half8v*)((char*)sW + ((row*256 + (cb ^ ((row & 7) << 4))))) = v;
    }
    __syncthreads();

    float4v acc[8];
    #pragma unroll
    for (int t = 0; t < 8; t++)
      #pragma unroll
      for (int i = 0; i < 4; i++) acc[t][i] = 0.f;

    #pragma unroll
    for (int t = 0; t < 8; t++){
      const int row = t*16 + l4;
      const int sw = (row & 7) << 4;
      #pragma unroll
      for (int ks = 0; ks < 4; ks++){
        half8v wf = *(const half8v*)((const char*)sW + (row*256 + ((ks*64 + kg*16) ^ sw)));
        acc[t] = __builtin_amdgcn_mfma_f32_16x16x32_f16(wf, xf[ks], acc[t], 0, 0, 0);
      }
    }

    const float* bo = (o == 0) ? b0 : (o == 1) ? b1 : b2;
    void* Yo = (o == 0) ? Y0 : (o == 1) ? Y1 : Y2;
    const int r = r0 + l4;
    if (r < nrows){
      #pragma unroll
      for (int t = 0; t < 8; t++){
        const int c = t*16 + kg*4;
        const float4 bb = *(const float4*)(bo + c);
        float v0 = acc[t][0] + bb.x, v1 = acc[t][1] + bb.y;
        float v2 = acc[t][2] + bb.z, v3 = acc[t][3] + bb.w;
        if (ACT){ v0=fmaxf(v0,0.f); v1=fmaxf(v1,0.f); v2=fmaxf(v2,0.f); v3=fmaxf(v3,0.f); }
        if (OMODE == 1 && o == 0){
          *(float4*)((float*)Yo + (size_t)r * ldy + c) = make_float4(v0, v1, v2, v3);
        } else if (OMODE == 2 && o > 0){
          unsigned int w01 = (unsigned int)__builtin_amdgcn_cvt_pk_fp8_f32(v0, v1, 0, false);
          unsigned int w   = (unsigned int)__builtin_amdgcn_cvt_pk_fp8_f32(v2, v3, (int)w01, true);
          *(unsigned int*)((unsigned char*)Yo + (size_t)r * FD + c) = w;
        } else {
          half4v hv;
          hv[0]=(_Float16)v0; hv[1]=(_Float16)v1; hv[2]=(_Float16)v2; hv[3]=(_Float16)v3;
          *(half4v*)((_Float16*)Yo + (size_t)r * ldy + c) = hv;
        }
      }
    }
  }
}

// ---------------- edge passes: quarter-wave (16 lanes)/node, 8 dims/lane, 4 edges/iter ----
#define SC 0.08838834764831845f

#define RED16(d) \
  d += __shfl_xor(d, 1); d += __shfl_xor(d, 2); d += __shfl_xor(d, 4); d += __shfl_xor(d, 8);

// scores1 (Qh . K8) fused with segment-mean of Xh -> SMh, and per-block online softmax partial
__global__ __launch_bounds__(256) void k_passA(const _Float16* __restrict__ Qh,
    const unsigned char* __restrict__ K8, const _Float16* __restrict__ Xh,
    const int* __restrict__ rowstart, const int* __restrict__ csrcol,
    float* __restrict__ scores, _Float16* __restrict__ SMh, int ldsm,
    float* __restrict__ pm, float* __restrict__ ps, int nnodes)
{
  __shared__ float red_m[256], red_s[256];
  const int tid = threadIdx.x;
  const int n = blockIdx.x * 16 + (tid >> 4);
  const int l4 = tid & 15;
  float om = -3.402823466e38f, os = 0.f;
  if (n < nnodes){
    const half8v qv = *(const half8v*)(Qh + (size_t)n * FD + 8*l4);
    float qf[8];
    #pragma unroll
    for (int i = 0; i < 8; i++) qf[i] = (float)qv[i];
    float sx[8];
    #pragma unroll
    for (int i = 0; i < 8; i++) sx[i] = 0.f;
    const int p0 = rowstart[n], p1 = rowstart[n+1];
    const int last = p1 - 1;
    for (int p = p0; p < p1; p += 4){
      int cc[4]; float mk[4];
      #pragma unroll
      for (int j = 0; j < 4; j++){
        const int idx = p + j;
        cc[j] = csrcol[idx < p1 ? idx : last];
        mk[j] = idx < p1 ? 1.f : 0.f;
      }
      uint2 ku[4]; half8v xv[4];
      #pragma unroll
      for (int j = 0; j < 4; j++){
        ku[j] = *(const uint2*)(K8 + (size_t)cc[j]*FD + 8*l4);
        xv[j] = *(const half8v*)(Xh + (size_t)cc[j]*FD + 8*l4);
      }
      float d[4];
      #pragma unroll
      for (int j = 0; j < 4; j++){
        float kf[8];
        dec8(ku[j].x, ku[j].y, kf);
        float t = 0.f;
        #pragma unroll
        for (int i = 0; i < 8; i++) t += qf[i] * kf[i];
        d[j] = t;
        #pragma unroll
        for (int i = 0; i < 8; i++) sx[i] += mk[j] * (float)xv[j][i];
      }
      #pragma unroll
      for (int j = 0; j < 4; j++){ RED16(d[j]) }
      const float sv = (l4==0) ? d[0] : (l4==1) ? d[1] : (l4==2) ? d[2] : d[3];
      if (l4 < 4 && p + l4 < p1){
        const float scv = sv * SC;
        scores[p + l4] = scv;
        OSM_PUSH(om, os, scv)
      }
    }
    int dg = p1 - p0; if (dg < 1) dg = 1;
    const float inv = 1.f / (float)dg;
    half8v o;
    #pragma unroll
    for (int i = 0; i < 8; i++) o[i] = (_Float16)(sx[i]*inv);
    *(half8v*)(SMh + (size_t)n * ldsm + 8*l4) = o;
  }
  // block-level online-softmax reduce (all threads participate)
  red_m[tid] = om; red_s[tid] = os;
  __syncthreads();
  for (int off = 128; off > 0; off >>= 1){
    if (tid < off){
      float m2 = red_m[tid + off], s2 = red_s[tid + off];
      float m1 = red_m[tid], s1 = red_s[tid];
      float Mx = fmaxf(m1, m2);
      red_m[tid] = Mx;
      red_s[tid] = s1 * __expf(m1 - Mx) + s2 * __expf(m2 - Mx);
    }
    __syncthreads();
  }
  if (tid == 0){ pm[blockIdx.x] = red_m[0]; ps[blockIdx.x] = red_s[0]; }
}

// scores (layer 2): Qh fp16, K8 fp8; fused per-block online softmax partial
__global__ __launch_bounds__(256) void k_scores2(const _Float16* __restrict__ Qh,
    const unsigned char* __restrict__ K8,
    const int* __restrict__ rowstart, const int* __restrict__ csrcol,
    float* __restrict__ scores, float* __restrict__ pm, float* __restrict__ ps, int nnodes)
{
  __shared__ float red_m[256], red_s[256];
  const int tid = threadIdx.x;
  const int n = blockIdx.x * 16 + (tid >> 4);
  const int l4 = tid & 15;
  float om = -3.402823466e38f, os = 0.f;
  if (n < nnodes){
    const int p0 = rowstart[n], p1 = rowstart[n+1];
    if (p0 < p1){
      const half8v qv = *(const half8v*)(Qh + (size_t)n * FD + 8*l4);
      float qf[8];
      #pragma unroll
      for (int i = 0; i < 8; i++) qf[i] = (float)qv[i];
      const int last = p1 - 1;
      for (int p = p0; p < p1; p += 4){
        int cc[4];
        #pragma unroll
        for (int j = 0; j < 4; j++){
          const int idx = p + j;
          cc[j] = csrcol[idx < p1 ? idx : last];
        }
        uint2 ku[4];
        #pragma unroll
        for (int j = 0; j < 4; j++)
          ku[j] = *(const uint2*)(K8 + (size_t)cc[j]*FD + 8*l4);
        float d[4];
        #pragma unroll
        for (int j = 0; j < 4; j++){
          float kf[8];
          dec8(ku[j].x, ku[j].y, kf);
          float t = 0.f;
          #pragma unroll
          for (int i = 0; i < 8; i++) t += qf[i] * kf[i];
          d[j] = t;
        }
        #pragma unroll
        for (int j = 0; j < 4; j++){ RED16(d[j]) }
        const float sv = (l4==0) ? d[0] : (l4==1) ? d[1] : (l4==2) ? d[2] : d[3];
        if (l4 < 4 && p + l4 < p1){
          const float scv = sv * SC;
          scores[p + l4] = scv;
          OSM_PUSH(om, os, scv)
        }
      }
    }
  }
  red_m[tid] = om; red_s[tid] = os;
  __syncthreads();
  for (int off = 128; off > 0; off >>= 1){
    if (tid < off){
      float m2 = red_m[tid + off], s2 = red_s[tid + off];
      float m1 = red_m[tid], s1 = red_s[tid];
      float Mx = fmaxf(m1, m2);
      red_m[tid] = Mx;
      red_s[tid] = s1 * __expf(m1 - Mx) + s2 * __expf(m2 - Mx);
    }
    __syncthreads();
  }
  if (tid == 0){ pm[blockIdx.x] = red_m[0]; ps[blockIdx.x] = red_s[0]; }
}

// message1 (alpha-weighted V8, ELU -> Ah fp16) fused with segment-mean of Sh -> Bh
__global__ __launch_bounds__(256) void k_passB(const unsigned char* __restrict__ V8,
    const _Float16* __restrict__ Sh,
    const float* __restrict__ sc, const float* __restrict__ Mp, const float* __restrict__ Ip,
    const int* __restrict__ rowstart, const int* __restrict__ csrcol,
    _Float16* __restrict__ Ah, _Float16* __restrict__ Bh, int ldb, int nnodes)
{
  const int tid = threadIdx.x;
  const int n = blockIdx.x * 16 + (tid >> 4);
  if (n >= nnodes) return;
  const int l4 = tid & 15;
  const float M = Mp[0], inv = Ip[0];
  float av[8], sv[8];
  #pragma unroll
  for (int i = 0; i < 8; i++){ av[i] = 0.f; sv[i] = 0.f; }
  const int p0 = rowstart[n], p1 = rowstart[n+1];
  const int last = p1 - 1;
  for (int p = p0; p < p1; p += 4){
    int cc[4]; float aa[4], mk[4];
    #pragma unroll
    for (int j = 0; j < 4; j++){
      const int idx = p + j;
      const int eff = idx < p1 ? idx : last;
      cc[j] = csrcol[eff];
      aa[j] = sc[eff];
      mk[j] = idx < p1 ? 1.f : 0.f;
    }
    uint2 vu[4]; half8v ss[4];
    #pragma unroll
    for (int j = 0; j < 4; j++){
      vu[j] = *(const uint2*)(V8 + (size_t)cc[j]*FD + 8*l4);
      ss[j] = *(const half8v*)(Sh + (size_t)cc[j]*FD + 8*l4);
    }
    #pragma unroll
    for (int j = 0; j < 4; j++){
      const float a = mk[j] * __expf(aa[j] - M);
      float vf[8];
      dec8(vu[j].x, vu[j].y, vf);
      #pragma unroll
      for (int i = 0; i < 8; i++){
        av[i] += a * vf[i];
        sv[i] += mk[j] * (float)ss[j][i];
      }
    }
  }
  #pragma unroll
  for (int i = 0; i < 8; i++){
    float v = av[i] * inv;
    av[i] = v > 0.f ? v : expm1f(v);
  }
  half8v oa;
  #pragma unroll
  for (int i = 0; i < 8; i++) oa[i] = (_Float16)av[i];
  *(half8v*)(Ah + (size_t)n * FD + 8*l4) = oa;
  int dg = p1 - p0; if (dg < 1) dg = 1;
  const float invd = 1.f / (float)dg;
  half8v ob;
  #pragma unroll
  for (int i = 0; i < 8; i++) ob[i] = (_Float16)(sv[i]*invd);
  *(half8v*)(Bh + (size_t)n * ldb + 8*l4) = ob;
}

// message2 -> out (fp32), V8 fp8
__global__ __launch_bounds__(256) void k_message2(const unsigned char* __restrict__ V8,
    const float* __restrict__ sc, const float* __restrict__ Mp, const float* __restrict__ Ip,
    const int* __restrict__ rowstart, const int* __restrict__ csrcol,
    float* __restrict__ out, int ldo, int nnodes)
{
  const int tid = threadIdx.x;
  const int n = blockIdx.x * 16 + (tid >> 4);
  if (n >= nnodes) return;
  const int l4 = tid & 15;
  const float M = Mp[0], inv = Ip[0];
  float av[8];
  #pragma unroll
  for (int i = 0; i < 8; i++) av[i] = 0.f;
  const int p0 = rowstart[n], p1 = rowstart[n+1];
  const int last = p1 - 1;
  for (int p = p0; p < p1; p += 4){
    int cc[4]; float aa[4], mk[4];
    #pragma unroll
    for (int j = 0; j < 4; j++){
      const int idx = p + j;
      const int eff = idx < p1 ? idx : last;
      cc[j] = csrcol[eff];
      aa[j] = sc[eff];
      mk[j] = idx < p1 ? 1.f : 0.f;
    }
    uint2 vu[4];
    #pragma unroll
    for (int j = 0; j < 4; j++)
      vu[j] = *(const uint2*)(V8 + (size_t)cc[j]*FD + 8*l4);
    #pragma unroll
    for (int j = 0; j < 4; j++){
      const float a = mk[j] * __expf(aa[j] - M);
      float vf[8];
      dec8(vu[j].x, vu[j].y, vf);
      #pragma unroll
      for (int i = 0; i < 8; i++) av[i] += a * vf[i];
    }
  }
  float* op = out + (size_t)n * ldo + 8*l4;
  *(float4*)(op    ) = make_float4(av[0]*inv, av[1]*inv, av[2]*inv, av[3]*inv);
  *(float4*)(op + 4) = make_float4(av[4]*inv, av[5]*inv, av[6]*inv, av[7]*inv);
}

// ---------------- final softmax reduce over per-block partials ----------------
__global__ __launch_bounds__(256) void k_sm_final(const float* __restrict__ pm, const float* __restrict__ ps,
    int n, float* __restrict__ Mout, float* __restrict__ Iout){
  __shared__ float sm_m[256], sm_s[256];
  const int tid = threadIdx.x;
  float m = -3.402823466e38f, sum = 0.f;
  for (int i = tid; i < n; i += 256){
    float m2 = pm[i], s2 = ps[i];
    float Mx = fmaxf(m, m2);
    sum = sum * __expf(m - Mx) + s2 * __expf(m2 - Mx);
    m = Mx;
  }
  sm_m[tid] = m; sm_s[tid] = sum; __syncthreads();
  for (int off = 128; off > 0; off >>= 1){
    if (tid < off){
      float m2 = sm_m[tid + off], s2 = sm_s[tid + off];
      float m1 = sm_m[tid], s1 = sm_s[tid];
      float Mx = fmaxf(m1, m2);
      sm_m[tid] = Mx;
      sm_s[tid] = s1 * __expf(m1 - Mx) + s2 * __expf(m2 - Mx);
    }
    __syncthreads();
  }
  if (tid == 0){ Mout[0] = sm_m[0]; Iout[0] = 1.f / sm_s[0]; }
}

extern "C" void kernel_launch(void* const* d_in, const int* in_sizes, int n_in,
                              void* d_out, int out_size, void* d_ws, size_t ws_size,
                              hipStream_t stream)
{
  const float* x   = (const float*)d_in[0];
  const int*   ei  = (const int*)d_in[1];
  const float* Wq1 = (const float*)d_in[2];  const float* bq1 = (const float*)d_in[3];
  const float* Wk1 = (const float*)d_in[4];  const float* bk1 = (const float*)d_in[5];
  const float* Wv1 = (const float*)d_in[6];  const float* bv1 = (const float*)d_in[7];
  const float* Wq2 = (const float*)d_in[8];  const float* bq2 = (const float*)d_in[9];
  const float* Wk2 = (const float*)d_in[10]; const float* bk2 = (const float*)d_in[11];
  const float* Wv2 = (const float*)d_in[12]; const float* bv2 = (const float*)d_in[13];
  const float* Ws1 = (const float*)d_in[14]; const float* bs1 = (const float*)d_in[15];
  const float* Ws2 = (const float*)d_in[16]; const float* bs2 = (const float*)d_in[17];

  const int N = in_sizes[0] / FD;
  const int E = in_sizes[1] / 2;
  const int* row = ei;
  const int* col = ei + E;
  float* out = (float*)d_out;

  char* ws = (char*)d_ws;
  size_t off = 0;
  auto alloc = [&](size_t bytes) -> void* {
    void* p = ws + off;
    off += (bytes + 255) & ~(size_t)255;
    return p;
  };
  const int nb = (N + 15) / 16;   // quarter-wave edge kernels: 16 nodes/block
  int* deg      = (int*)alloc((size_t)N * 4);
  int* rowstart = (int*)alloc((size_t)(N + 1) * 4);
  int* csrcol   = (int*)alloc((size_t)E * 4);
  uint2* pairs  = (uint2*)alloc((size_t)E * 8);
  int* bhist    = (int*)alloc(1024);
  int* bstart   = (int*)alloc(1056);
  int* bcursor  = (int*)alloc(1024);
  float* scores = (float*)alloc((size_t)E * 4);
  int* blksum   = (int*)alloc(1024);
  int* blkoff   = (int*)alloc(1024);
  float* pm     = (float*)alloc((size_t)nb * 4);
  float* ps     = (float*)alloc((size_t)nb * 4);
  float* Mv     = (float*)alloc(256);
  float* Iv     = (float*)alloc(256);
  _Float16* Xh = (_Float16*)alloc((size_t)N * FD * 2);   // x fp16; aliased as Sh after passA
  _Float16* Qh = (_Float16*)alloc((size_t)N * FD * 2);
  unsigned char* K8 = (unsigned char*)alloc((size_t)N * FD);
  unsigned char* V8 = (unsigned char*)alloc((size_t)N * FD);
  _Float16* Ah = (_Float16*)alloc((size_t)N * FD * 2);
  _Float16* Wh = (_Float16*)alloc((size_t)8 * FD * FD * 2);
  _Float16* Sh = Xh;                 // s1: Xh dead after passA
  _Float16* SMBh = (_Float16*)out;   // seg-mean scratch inside out cols[0,128) bytes, ld 512 halfs
  (void)ws_size; (void)n_in; (void)out_size;

  hipMemsetAsync(bhist, 0, 1024, stream);

  // conversions (one kernel: 8 weight matrices + x)
  k_cvt_all<<<2048, 256, 0, stream>>>((const float4*)x, (half4v*)Xh, N * FD / 4,
      Wq1, Wk1, Wv1, Wq2, Wk2, Wv2, Ws1, Ws2, Wh);

  // ---- bucketed CSR build ----
  const int nbuckets = (N + 255) >> 8;
  const int nblk = (N + 1023) / 1024;
  k_bhist<<<1024, 256, 0, stream>>>(row, E, bhist);
  k_bscan<<<1, 256, 0, stream>>>(bhist, bstart, bcursor, E);
  k_bscatter<<<256, 256, 0, stream>>>(row, col, E, bstart, bcursor, pairs);
  k_bdeg<<<nbuckets, 256, 0, stream>>>(pairs, bstart, N, deg);
  k_scan_blk<<<nblk, 256, 0, stream>>>(deg, N, rowstart, blksum);
  k_scan_part<<<1, 256, 0, stream>>>(blksum, nblk, blkoff);
  k_scan_add<<<(N + 255)/256, 256, 0, stream>>>(rowstart, N, blkoff, E);
  k_bfill<<<nbuckets, 256, 0, stream>>>(pairs, bstart, rowstart, N, csrcol);

  const int gb = (N + 63) / 64;

  // ---- layer-1 QKV (LDS-staged MFMA f16; Q fp16, K/V fp8) ----
  k_gemm_lds<3,0,2><<<gb, 256, 0, stream>>>(Xh, FD, Wh + 0*FD*FD,
      bq1, Qh, bk1, K8, bv1, V8, FD, N);

  // ---- fused: scores1 + seg_mean(Xh) -> SMBh + per-block softmax partials ----
  k_passA<<<nb, 256, 0, stream>>>(Qh, K8, Xh, rowstart, csrcol, scores, SMBh, 512, pm, ps, N);
  k_sm_final<<<1, 256, 0, stream>>>(pm, ps, nb, Mv, Iv);

  // s1 = relu(SMBh @ Ws1^T + bs1) -> Sh (fp16 packed; overwrites dead Xh)
  k_gemm_lds<1,1,0><<<gb, 256, 0, stream>>>(SMBh, 512, Wh + 6*FD*FD,
      bs1, Sh, nullptr, nullptr, nullptr, nullptr, FD, N);

  // ---- fused: message1+ELU -> Ah; seg_mean(s1) -> Bh (= SMBh region, SM dead) ----
  k_passB<<<nb, 256, 0, stream>>>(V8, Sh, scores, Mv, Iv, rowstart, csrcol, Ah, SMBh, 512, N);

  // ss_out = relu(Bh @ Ws2^T + bs2) -> out cols [128,256) fp32
  k_gemm_lds<1,1,1><<<gb, 256, 0, stream>>>(SMBh, 512, Wh + 7*FD*FD,
      bs2, out + FD, nullptr, nullptr, nullptr, nullptr, 2*FD, N);

  // ---- layer-2 QKV (overwrites Qh/K8/V8 after passB consumed V8) ----
  k_gemm_lds<3,0,2><<<gb, 256, 0, stream>>>(Ah, FD, Wh + 3*FD*FD,
      bq2, Qh, bk2, K8, bv2, V8, FD, N);
  k_scores2<<<nb, 256, 0, stream>>>(Qh, K8, rowstart, csrcol, scores, pm, ps, N);
  k_sm_final<<<1, 256, 0, stream>>>(pm, ps, nb, Mv, Iv);

  // message2 -> out cols [0,128) fp32
  k_message2<<<nb, 256, 0, stream>>>(V8, scores, Mv, Iv, rowstart, csrcol, out, 2*FD, N);
}

// Round 12
// 298.445 us; speedup vs baseline: 1.0322x; 1.0102x over previous
//
#include <hip/hip_runtime.h>
#include <math.h>

#define FD 128
#define REC 384   // packed record: 128 B fp8 row + 256 B fp16 row

typedef __attribute__((ext_vector_type(8))) _Float16 half8v;
typedef __attribute__((ext_vector_type(4))) _Float16 half4v;
typedef __attribute__((ext_vector_type(4))) float float4v;
typedef __attribute__((ext_vector_type(2))) float floatx2;

static __device__ __forceinline__ void dec8(unsigned int lo, unsigned int hi, float* f){
  floatx2 a = __builtin_amdgcn_cvt_pk_f32_fp8(lo, false);
  floatx2 b = __builtin_amdgcn_cvt_pk_f32_fp8(lo, true);
  floatx2 c = __builtin_amdgcn_cvt_pk_f32_fp8(hi, false);
  floatx2 d = __builtin_amdgcn_cvt_pk_f32_fp8(hi, true);
  f[0]=a[0]; f[1]=a[1]; f[2]=b[0]; f[3]=b[1];
  f[4]=c[0]; f[5]=c[1]; f[6]=d[0]; f[7]=d[1];
}

// online-softmax lane update
#define OSM_PUSH(om, os, v) \
  { if ((v) <= om) os += __expf((v) - om); \
    else { os = os * __expf(om - (v)) + 1.f; om = (v); } }

// ---------------- combined conversions: 8 weight mats -> fp16, x -> fp16 (+ PA record copy) ----
__global__ void k_cvt_all(const float4* __restrict__ x4, half4v* __restrict__ Xh4, int n4x,
    unsigned char* __restrict__ PA,
    const float* __restrict__ w0, const float* __restrict__ w1, const float* __restrict__ w2,
    const float* __restrict__ w3, const float* __restrict__ w4, const float* __restrict__ w5,
    const float* __restrict__ w6, const float* __restrict__ w7, _Float16* __restrict__ Wh){
  const int nw4 = 8 * FD * FD / 4;
  int i = blockIdx.x * 256 + threadIdx.x, st = gridDim.x * 256;
  for (; i < nw4 + n4x; i += st){
    if (i < nw4){
      const int m = i >> 12;
      const int e = (i & 4095) << 2;
      const float* wm = (m==0)?w0:(m==1)?w1:(m==2)?w2:(m==3)?w3:(m==4)?w4:(m==5)?w5:(m==6)?w6:w7;
      float4 v = *(const float4*)(wm + e);
      half4v o;
      o[0]=(_Float16)v.x; o[1]=(_Float16)v.y; o[2]=(_Float16)v.z; o[3]=(_Float16)v.w;
      *(half4v*)(Wh + (size_t)m * FD * FD + e) = o;
    } else {
      const int j = i - nw4;
      float4 v = x4[j];
      half4v o;
      o[0]=(_Float16)v.x; o[1]=(_Float16)v.y; o[2]=(_Float16)v.z; o[3]=(_Float16)v.w;
      Xh4[j] = o;
      const int r = j >> 5;            // 32 half4-units per 128-elem row
      const int c4 = j & 31;
      *(half4v*)(PA + (size_t)r * REC + 128 + c4*8) = o;
    }
  }
}

// ---------------- CSR build (bucketed, low write-amplification) ----------------
__global__ __launch_bounds__(256) void k_bhist(const int* __restrict__ row, int E,
    int* __restrict__ bhist){
  __shared__ int h[256];
  h[threadIdx.x] = 0; __syncthreads();
  for (int i = blockIdx.x*256 + threadIdx.x; i < E; i += gridDim.x*256)
    atomicAdd(&h[row[i] >> 8], 1);
  __syncthreads();
  int v = h[threadIdx.x];
  if (v) atomicAdd(&bhist[threadIdx.x], v);
}

__global__ __launch_bounds__(256) void k_bscan(const int* __restrict__ bhist,
    int* __restrict__ bstart, int* __restrict__ bcursor, int E){
  __shared__ int sm[256];
  const int tid = threadIdx.x;
  int v = bhist[tid];
  sm[tid] = v; __syncthreads();
  for (int off = 1; off < 256; off <<= 1){
    int t = (tid >= off) ? sm[tid-off] : 0;
    __syncthreads();
    sm[tid] += t;
    __syncthreads();
  }
  bstart[tid] = sm[tid] - v;
  if (tid == 255) bstart[256] = E;
  bcursor[tid] = 0;
}

__global__ __launch_bounds__(256) void k_bscatter(const int* __restrict__ row,
    const int* __restrict__ col, int E, const int* __restrict__ bstart,
    int* __restrict__ bcursor, uint2* __restrict__ pairs){
  __shared__ int cnt[256];
  __shared__ int base[256];
  const int tid = threadIdx.x;
  const int per = (E + gridDim.x - 1) / gridDim.x;
  const int lo = blockIdx.x * per;
  const int hi = min(E, lo + per);
  cnt[tid] = 0; __syncthreads();
  for (int i = lo + tid; i < hi; i += 256)
    atomicAdd(&cnt[row[i] >> 8], 1);
  __syncthreads();
  base[tid] = cnt[tid] ? atomicAdd(&bcursor[tid], cnt[tid]) : 0;
  __syncthreads();
  cnt[tid] = 0; __syncthreads();
  for (int i = lo + tid; i < hi; i += 256){
    const int r = row[i];
    const int b = r >> 8;
    const int loc = atomicAdd(&cnt[b], 1);
    pairs[(size_t)bstart[b] + base[b] + loc] = make_uint2((unsigned)r, (unsigned)col[i]);
  }
}

__global__ __launch_bounds__(256) void k_bdeg(const uint2* __restrict__ pairs,
    const int* __restrict__ bstart, int N, int* __restrict__ deg){
  __shared__ int cnt[256];
  const int b = blockIdx.x, tid = threadIdx.x;
  cnt[tid] = 0; __syncthreads();
  const int lo = bstart[b], hi = bstart[b+1];
  for (int i = lo + tid; i < hi; i += 256)
    atomicAdd(&cnt[pairs[i].x & 255], 1);
  __syncthreads();
  const int r = (b << 8) + tid;
  if (r < N) deg[r] = cnt[tid];
}

__global__ __launch_bounds__(256) void k_bfill(const uint2* __restrict__ pairs,
    const int* __restrict__ bstart, const int* __restrict__ rowstart, int N,
    int* __restrict__ csrcol){
  __shared__ int base[256];
  __shared__ int cur[256];
  const int b = blockIdx.x, tid = threadIdx.x;
  const int r = (b << 8) + tid;
  base[tid] = (r < N) ? rowstart[r] : 0;
  cur[tid] = 0;
  __syncthreads();
  const int lo = bstart[b], hi = bstart[b+1];
  for (int i = lo + tid; i < hi; i += 256){
    uint2 p = pairs[i];
    const int rl = p.x & 255;
    const int loc = atomicAdd(&cur[rl], 1);
    csrcol[base[rl] + loc] = (int)p.y;
  }
}

// ---------------- deg scan -> rowstart ----------------
__global__ __launch_bounds__(256) void k_scan_blk(const int* __restrict__ in, int n,
    int* __restrict__ out, int* __restrict__ blksum){
  __shared__ int sm[256];
  const int tid = threadIdx.x;
  const int base = blockIdx.x * 1024;
  const int idx = base + tid * 4;
  int v0=0,v1=0,v2=0,v3=0;
  if (idx + 3 < n){ int4 t = *(const int4*)(in + idx); v0=t.x; v1=t.y; v2=t.z; v3=t.w; }
  else {
    if (idx   < n) v0 = in[idx];
    if (idx+1 < n) v1 = in[idx+1];
    if (idx+2 < n) v2 = in[idx+2];
    if (idx+3 < n) v3 = in[idx+3];
  }
  int s = v0+v1+v2+v3;
  sm[tid] = s; __syncthreads();
  for (int off = 1; off < 256; off <<= 1){
    int t = (tid >= off) ? sm[tid-off] : 0;
    __syncthreads();
    sm[tid] += t;
    __syncthreads();
  }
  int excl = sm[tid] - s;
  if (tid == 255) blksum[blockIdx.x] = sm[255];
  if (idx   < n) out[idx]   = excl;
  if (idx+1 < n) out[idx+1] = excl + v0;
  if (idx+2 < n) out[idx+2] = excl + v0 + v1;
  if (idx+3 < n) out[idx+3] = excl + v0 + v1 + v2;
}

__global__ __launch_bounds__(256) void k_scan_part(const int* __restrict__ blksum, int nblk,
    int* __restrict__ blkoff){
  __shared__ int sm[256];
  const int tid = threadIdx.x;
  int v = (tid < nblk) ? blksum[tid] : 0;
  sm[tid] = v; __syncthreads();
  for (int off = 1; off < 256; off <<= 1){
    int t = (tid >= off) ? sm[tid-off] : 0;
    __syncthreads();
    sm[tid] += t;
    __syncthreads();
  }
  if (tid < nblk) blkoff[tid] = sm[tid] - v;
}

__global__ __launch_bounds__(256) void k_scan_add(int* __restrict__ out, int n,
    const int* __restrict__ blkoff, int E){
  int i = blockIdx.x * 256 + threadIdx.x;
  if (i < n) out[i] += blkoff[i >> 10];
  if (i == 0) out[n] = E;
}

// ---------------- LDS-staged MFMA f16 GEMM (1..3 outputs) ----------------
// OMODE: 0 = all outputs fp16 (ld0 halfs); 1 = output0 fp32 (ld0 floats);
// OMODE 2 = QKV: out0 fp16 (ld0 halfs), out1/out2 fp8 e4m3 (ld1/ld2 BYTE strides)
template<int NOUT, int ACT, int OMODE>
__global__ __launch_bounds__(256) void k_gemm_lds(const _Float16* __restrict__ X, int ldx,
    const _Float16* __restrict__ W,
    const float* __restrict__ b0, void* __restrict__ Y0,
    const float* __restrict__ b1, void* __restrict__ Y1,
    const float* __restrict__ b2, void* __restrict__ Y2,
    int ld0, int ld1, int ld2, int nrows)
{
  __shared__ _Float16 sW[FD * FD];    // 32 KB
  const int tid  = threadIdx.x;
  const int wid  = tid >> 6;
  const int lane = tid & 63;
  const int l4 = lane & 15;
  const int kg = lane >> 4;
  const int r0 = blockIdx.x * 64 + wid * 16;

  int rA = r0 + l4; if (rA > nrows - 1) rA = nrows - 1;
  half8v xf[4];
  #pragma unroll
  for (int ks = 0; ks < 4; ks++)
    xf[ks] = *(const half8v*)(X + (size_t)rA * ldx + ks*32 + kg*8);

  for (int o = 0; o < NOUT; o++){
    if (o) __syncthreads();
    const _Float16* Wo = W + (size_t)o * FD * FD;
    #pragma unroll
    for (int j = 0; j < 8; j++){
      const int b = j*4096 + tid*16;
      const int row = b >> 8, cb = b & 255;
      half8v v = *(const half8v*)((const char*)Wo + b);
      *(half8v*)((char*)sW + ((row*256 + (cb ^ ((row & 7) << 4))))) = v;
    }
    __syncthreads();

    float4v acc[8];
    #pragma unroll
    for (int t = 0; t < 8; t++)
      #pragma unroll
      for (int i = 0; i < 4; i++) acc[t][i] = 0.f;

    #pragma unroll
    for (int t = 0; t < 8; t++){
      const int row = t*16 + l4;
      const int sw = (row & 7) << 4;
      #pragma unroll
      for (int ks = 0; ks < 4; ks++){
        half8v wf = *(const half8v*)((const char*)sW + (row*256 + ((ks*64 + kg*16) ^ sw)));
        acc[t] = __builtin_amdgcn_mfma_f32_16x16x32_f16(wf, xf[ks], acc[t], 0, 0, 0);
      }
    }

    const float* bo = (o == 0) ? b0 : (o == 1) ? b1 : b2;
    void* Yo = (o == 0) ? Y0 : (o == 1) ? Y1 : Y2;
    const int r = r0 + l4;
    if (r < nrows){
      #pragma unroll
      for (int t = 0; t < 8; t++){
        const int c = t*16 + kg*4;
        const float4 bb = *(const float4*)(bo + c);
        float v0 = acc[t][0] + bb.x, v1 = acc[t][1] + bb.y;
        float v2 = acc[t][2] + bb.z, v3 = acc[t][3] + bb.w;
        if (ACT){ v0=fmaxf(v0,0.f); v1=fmaxf(v1,0.f); v2=fmaxf(v2,0.f); v3=fmaxf(v3,0.f); }
        if (OMODE == 1 && o == 0){
          *(float4*)((float*)Yo + (size_t)r * ld0 + c) = make_float4(v0, v1, v2, v3);
        } else if (OMODE == 2 && o > 0){
          const int ldb = (o == 1) ? ld1 : ld2;   // BYTE stride
          unsigned int w01 = (unsigned int)__builtin_amdgcn_cvt_pk_fp8_f32(v0, v1, 0, false);
          unsigned int w   = (unsigned int)__builtin_amdgcn_cvt_pk_fp8_f32(v2, v3, (int)w01, true);
          *(unsigned int*)((unsigned char*)Yo + (size_t)r * ldb + c) = w;
        } else {
          half4v hv;
          hv[0]=(_Float16)v0; hv[1]=(_Float16)v1; hv[2]=(_Float16)v2; hv[3]=(_Float16)v3;
          *(half4v*)((_Float16*)Yo + (size_t)r * ld0 + c) = hv;
        }
      }
    }
  }
}

// ---------------- edge passes: quarter-wave (16 lanes)/node, 8 dims/lane, 4 edges/iter ----
#define SC 0.08838834764831845f

#define RED16(d) \
  d += __shfl_xor(d, 1); d += __shfl_xor(d, 2); d += __shfl_xor(d, 4); d += __shfl_xor(d, 8);

// scores1 (Qh . PA.K8) fused with seg_mean(PA.Xh) -> SMh, and per-block online softmax partial
__global__ __launch_bounds__(256) void k_passA(const _Float16* __restrict__ Qh,
    const unsigned char* __restrict__ PA,
    const int* __restrict__ rowstart, const int* __restrict__ csrcol,
    float* __restrict__ scores, _Float16* __restrict__ SMh, int ldsm,
    float* __restrict__ pm, float* __restrict__ ps, int nnodes)
{
  __shared__ float red_m[256], red_s[256];
  const int tid = threadIdx.x;
  const int n = blockIdx.x * 16 + (tid >> 4);
  const int l4 = tid & 15;
  float om = -3.402823466e38f, os = 0.f;
  if (n < nnodes){
    const half8v qv = *(const half8v*)(Qh + (size_t)n * FD + 8*l4);
    float qf[8];
    #pragma unroll
    for (int i = 0; i < 8; i++) qf[i] = (float)qv[i];
    float sx[8];
    #pragma unroll
    for (int i = 0; i < 8; i++) sx[i] = 0.f;
    const int p0 = rowstart[n], p1 = rowstart[n+1];
    const int last = p1 - 1;
    for (int p = p0; p < p1; p += 4){
      int cc[4]; float mk[4];
      #pragma unroll
      for (int j = 0; j < 4; j++){
        const int idx = p + j;
        cc[j] = csrcol[idx < p1 ? idx : last];
        mk[j] = idx < p1 ? 1.f : 0.f;
      }
      uint2 ku[4]; half8v xv[4];
      #pragma unroll
      for (int j = 0; j < 4; j++){
        const unsigned char* rec = PA + (size_t)cc[j] * REC;
        ku[j] = *(const uint2*)(rec + 8*l4);
        xv[j] = *(const half8v*)(rec + 128 + 16*l4);
      }
      float d[4];
      #pragma unroll
      for (int j = 0; j < 4; j++){
        float kf[8];
        dec8(ku[j].x, ku[j].y, kf);
        float t = 0.f;
        #pragma unroll
        for (int i = 0; i < 8; i++) t += qf[i] * kf[i];
        d[j] = t;
        #pragma unroll
        for (int i = 0; i < 8; i++) sx[i] += mk[j] * (float)xv[j][i];
      }
      #pragma unroll
      for (int j = 0; j < 4; j++){ RED16(d[j]) }
      const float sv = (l4==0) ? d[0] : (l4==1) ? d[1] : (l4==2) ? d[2] : d[3];
      if (l4 < 4 && p + l4 < p1){
        const float scv = sv * SC;
        scores[p + l4] = scv;
        OSM_PUSH(om, os, scv)
      }
    }
    int dg = p1 - p0; if (dg < 1) dg = 1;
    const float inv = 1.f / (float)dg;
    half8v o;
    #pragma unroll
    for (int i = 0; i < 8; i++) o[i] = (_Float16)(sx[i]*inv);
    *(half8v*)(SMh + (size_t)n * ldsm + 8*l4) = o;
  }
  red_m[tid] = om; red_s[tid] = os;
  __syncthreads();
  for (int off = 128; off > 0; off >>= 1){
    if (tid < off){
      float m2 = red_m[tid + off], s2 = red_s[tid + off];
      float m1 = red_m[tid], s1 = red_s[tid];
      float Mx = fmaxf(m1, m2);
      red_m[tid] = Mx;
      red_s[tid] = s1 * __expf(m1 - Mx) + s2 * __expf(m2 - Mx);
    }
    __syncthreads();
  }
  if (tid == 0){ pm[blockIdx.x] = red_m[0]; ps[blockIdx.x] = red_s[0]; }
}

// scores (layer 2): Qh fp16, K8 fp8 plain; fused per-block online softmax partial
__global__ __launch_bounds__(256) void k_scores2(const _Float16* __restrict__ Qh,
    const unsigned char* __restrict__ K8,
    const int* __restrict__ rowstart, const int* __restrict__ csrcol,
    float* __restrict__ scores, float* __restrict__ pm, float* __restrict__ ps, int nnodes)
{
  __shared__ float red_m[256], red_s[256];
  const int tid = threadIdx.x;
  const int n = blockIdx.x * 16 + (tid >> 4);
  const int l4 = tid & 15;
  float om = -3.402823466e38f, os = 0.f;
  if (n < nnodes){
    const int p0 = rowstart[n], p1 = rowstart[n+1];
    if (p0 < p1){
      const half8v qv = *(const half8v*)(Qh + (size_t)n * FD + 8*l4);
      float qf[8];
      #pragma unroll
      for (int i = 0; i < 8; i++) qf[i] = (float)qv[i];
      const int last = p1 - 1;
      for (int p = p0; p < p1; p += 4){
        int cc[4];
        #pragma unroll
        for (int j = 0; j < 4; j++){
          const int idx = p + j;
          cc[j] = csrcol[idx < p1 ? idx : last];
        }
        uint2 ku[4];
        #pragma unroll
        for (int j = 0; j < 4; j++)
          ku[j] = *(const uint2*)(K8 + (size_t)cc[j]*FD + 8*l4);
        float d[4];
        #pragma unroll
        for (int j = 0; j < 4; j++){
          float kf[8];
          dec8(ku[j].x, ku[j].y, kf);
          float t = 0.f;
          #pragma unroll
          for (int i = 0; i < 8; i++) t += qf[i] * kf[i];
          d[j] = t;
        }
        #pragma unroll
        for (int j = 0; j < 4; j++){ RED16(d[j]) }
        const float sv = (l4==0) ? d[0] : (l4==1) ? d[1] : (l4==2) ? d[2] : d[3];
        if (l4 < 4 && p + l4 < p1){
          const float scv = sv * SC;
          scores[p + l4] = scv;
          OSM_PUSH(om, os, scv)
        }
      }
    }
  }
  red_m[tid] = om; red_s[tid] = os;
  __syncthreads();
  for (int off = 128; off > 0; off >>= 1){
    if (tid < off){
      float m2 = red_m[tid + off], s2 = red_s[tid + off];
      float m1 = red_m[tid], s1 = red_s[tid];
      float Mx = fmaxf(m1, m2);
      red_m[tid] = Mx;
      red_s[tid] = s1 * __expf(m1 - Mx) + s2 * __expf(m2 - Mx);
    }
    __syncthreads();
  }
  if (tid == 0){ pm[blockIdx.x] = red_m[0]; ps[blockIdx.x] = red_s[0]; }
}

// message1 (alpha-weighted PB.V8, ELU -> Ah fp16) fused with seg_mean(PB.Sh) -> Bh
__global__ __launch_bounds__(256) void k_passB(const unsigned char* __restrict__ PB,
    const float* __restrict__ sc, const float* __restrict__ Mp, const float* __restrict__ Ip,
    const int* __restrict__ rowstart, const int* __restrict__ csrcol,
    _Float16* __restrict__ Ah, _Float16* __restrict__ Bh, int ldb, int nnodes)
{
  const int tid = threadIdx.x;
  const int n = blockIdx.x * 16 + (tid >> 4);
  if (n >= nnodes) return;
  const int l4 = tid & 15;
  const float M = Mp[0], inv = Ip[0];
  float av[8], sv[8];
  #pragma unroll
  for (int i = 0; i < 8; i++){ av[i] = 0.f; sv[i] = 0.f; }
  const int p0 = rowstart[n], p1 = rowstart[n+1];
  const int last = p1 - 1;
  for (int p = p0; p < p1; p += 4){
    int cc[4]; float aa[4], mk[4];
    #pragma unroll
    for (int j = 0; j < 4; j++){
      const int idx = p + j;
      const int eff = idx < p1 ? idx : last;
      cc[j] = csrcol[eff];
      aa[j] = sc[eff];
      mk[j] = idx < p1 ? 1.f : 0.f;
    }
    uint2 vu[4]; half8v ss[4];
    #pragma unroll
    for (int j = 0; j < 4; j++){
      const unsigned char* rec = PB + (size_t)cc[j] * REC;
      vu[j] = *(const uint2*)(rec + 8*l4);
      ss[j] = *(const half8v*)(rec + 128 + 16*l4);
    }
    #pragma unroll
    for (int j = 0; j < 4; j++){
      const float a = mk[j] * __expf(aa[j] - M);
      float vf[8];
      dec8(vu[j].x, vu[j].y, vf);
      #pragma unroll
      for (int i = 0; i < 8; i++){
        av[i] += a * vf[i];
        sv[i] += mk[j] * (float)ss[j][i];
      }
    }
  }
  #pragma unroll
  for (int i = 0; i < 8; i++){
    float v = av[i] * inv;
    av[i] = v > 0.f ? v : expm1f(v);
  }
  half8v oa;
  #pragma unroll
  for (int i = 0; i < 8; i++) oa[i] = (_Float16)av[i];
  *(half8v*)(Ah + (size_t)n * FD + 8*l4) = oa;
  int dg = p1 - p0; if (dg < 1) dg = 1;
  const float invd = 1.f / (float)dg;
  half8v ob;
  #pragma unroll
  for (int i = 0; i < 8; i++) ob[i] = (_Float16)(sv[i]*invd);
  *(half8v*)(Bh + (size_t)n * ldb + 8*l4) = ob;
}

// message2 -> out (fp32), V8 fp8 plain
__global__ __launch_bounds__(256) void k_message2(const unsigned char* __restrict__ V8,
    const float* __restrict__ sc, const float* __restrict__ Mp, const float* __restrict__ Ip,
    const int* __restrict__ rowstart, const int* __restrict__ csrcol,
    float* __restrict__ out, int ldo, int nnodes)
{
  const int tid = threadIdx.x;
  const int n = blockIdx.x * 16 + (tid >> 4);
  if (n >= nnodes) return;
  const int l4 = tid & 15;
  const float M = Mp[0], inv = Ip[0];
  float av[8];
  #pragma unroll
  for (int i = 0; i < 8; i++) av[i] = 0.f;
  const int p0 = rowstart[n], p1 = rowstart[n+1];
  const int last = p1 - 1;
  for (int p = p0; p < p1; p += 4){
    int cc[4]; float aa[4], mk[4];
    #pragma unroll
    for (int j = 0; j < 4; j++){
      const int idx = p + j;
      const int eff = idx < p1 ? idx : last;
      cc[j] = csrcol[eff];
      aa[j] = sc[eff];
      mk[j] = idx < p1 ? 1.f : 0.f;
    }
    uint2 vu[4];
    #pragma unroll
    for (int j = 0; j < 4; j++)
      vu[j] = *(const uint2*)(V8 + (size_t)cc[j]*FD + 8*l4);
    #pragma unroll
    for (int j = 0; j < 4; j++){
      const float a = mk[j] * __expf(aa[j] - M);
      float vf[8];
      dec8(vu[j].x, vu[j].y, vf);
      #pragma unroll
      for (int i = 0; i < 8; i++) av[i] += a * vf[i];
    }
  }
  float* op = out + (size_t)n * ldo + 8*l4;
  *(float4*)(op    ) = make_float4(av[0]*inv, av[1]*inv, av[2]*inv, av[3]*inv);
  *(float4*)(op + 4) = make_float4(av[4]*inv, av[5]*inv, av[6]*inv, av[7]*inv);
}

// ---------------- final softmax reduce over per-block partials ----------------
__global__ __launch_bounds__(256) void k_sm_final(const float* __restrict__ pm, const float* __restrict__ ps,
    int n, float* __restrict__ Mout, float* __restrict__ Iout){
  __shared__ float sm_m[256], sm_s[256];
  const int tid = threadIdx.x;
  float m = -3.402823466e38f, sum = 0.f;
  for (int i = tid; i < n; i += 256){
    float m2 = pm[i], s2 = ps[i];
    float Mx = fmaxf(m, m2);
    sum = sum * __expf(m - Mx) + s2 * __expf(m2 - Mx);
    m = Mx;
  }
  sm_m[tid] = m; sm_s[tid] = sum; __syncthreads();
  for (int off = 128; off > 0; off >>= 1){
    if (tid < off){
      float m2 = sm_m[tid + off], s2 = sm_s[tid + off];
      float m1 = sm_m[tid], s1 = sm_s[tid];
      float Mx = fmaxf(m1, m2);
      sm_m[tid] = Mx;
      sm_s[tid] = s1 * __expf(m1 - Mx) + s2 * __expf(m2 - Mx);
    }
    __syncthreads();
  }
  if (tid == 0){ Mout[0] = sm_m[0]; Iout[0] = 1.f / sm_s[0]; }
}

extern "C" void kernel_launch(void* const* d_in, const int* in_sizes, int n_in,
                              void* d_out, int out_size, void* d_ws, size_t ws_size,
                              hipStream_t stream)
{
  const float* x   = (const float*)d_in[0];
  const int*   ei  = (const int*)d_in[1];
  const float* Wq1 = (const float*)d_in[2];  const float* bq1 = (const float*)d_in[3];
  const float* Wk1 = (const float*)d_in[4];  const float* bk1 = (const float*)d_in[5];
  const float* Wv1 = (const float*)d_in[6];  const float* bv1 = (const float*)d_in[7];
  const float* Wq2 = (const float*)d_in[8];  const float* bq2 = (const float*)d_in[9];
  const float* Wk2 = (const float*)d_in[10]; const float* bk2 = (const float*)d_in[11];
  const float* Wv2 = (const float*)d_in[12]; const float* bv2 = (const float*)d_in[13];
  const float* Ws1 = (const float*)d_in[14]; const float* bs1 = (const float*)d_in[15];
  const float* Ws2 = (const float*)d_in[16]; const float* bs2 = (const float*)d_in[17];

  const int N = in_sizes[0] / FD;
  const int E = in_sizes[1] / 2;
  const int* row = ei;
  const int* col = ei + E;
  float* out = (float*)d_out;

  char* ws = (char*)d_ws;
  size_t off = 0;
  auto alloc = [&](size_t bytes) -> void* {
    void* p = ws + off;
    off += (bytes + 255) & ~(size_t)255;
    return p;
  };
  const int nb = (N + 15) / 16;   // quarter-wave edge kernels: 16 nodes/block
  int* deg      = (int*)alloc((size_t)N * 4);
  int* rowstart = (int*)alloc((size_t)(N + 1) * 4);
  int* csrcol   = (int*)alloc((size_t)E * 4);
  uint2* pairs  = (uint2*)alloc((size_t)E * 8);
  int* bhist    = (int*)alloc(1024);
  int* bstart   = (int*)alloc(1056);
  int* bcursor  = (int*)alloc(1024);
  float* scores = (float*)alloc((size_t)E * 4);
  int* blksum   = (int*)alloc(1024);
  int* blkoff   = (int*)alloc(1024);
  float* pm     = (float*)alloc((size_t)nb * 4);
  float* ps     = (float*)alloc((size_t)nb * 4);
  float* Mv     = (float*)alloc(256);
  float* Iv     = (float*)alloc(256);
  _Float16* Xh = (_Float16*)alloc((size_t)N * FD * 2);            // x fp16 (GEMM input)
  _Float16* Qh = (_Float16*)alloc((size_t)N * FD * 2);
  unsigned char* PA = (unsigned char*)alloc((size_t)N * REC);     // {K8 | Xh} records
  unsigned char* PB = (unsigned char*)alloc((size_t)N * REC);     // {V8 | Sh} records
  unsigned char* K8 = (unsigned char*)alloc((size_t)N * FD);      // layer-2 K
  unsigned char* V8 = (unsigned char*)alloc((size_t)N * FD);      // layer-2 V
  _Float16* Ah = (_Float16*)alloc((size_t)N * FD * 2);
  _Float16* Wh = (_Float16*)alloc((size_t)8 * FD * FD * 2);
  _Float16* SMBh = (_Float16*)out;   // seg-mean scratch inside out cols[0,128) bytes, ld 512 halfs
  (void)ws_size; (void)n_in; (void)out_size;

  hipMemsetAsync(bhist, 0, 1024, stream);

  // conversions (weights + x -> fp16; x also mirrored into PA record slot 1)
  k_cvt_all<<<2048, 256, 0, stream>>>((const float4*)x, (half4v*)Xh, N * FD / 4, PA,
      Wq1, Wk1, Wv1, Wq2, Wk2, Wv2, Ws1, Ws2, Wh);

  // ---- bucketed CSR build ----
  const int nbuckets = (N + 255) >> 8;
  const int nblk = (N + 1023) / 1024;
  k_bhist<<<1024, 256, 0, stream>>>(row, E, bhist);
  k_bscan<<<1, 256, 0, stream>>>(bhist, bstart, bcursor, E);
  k_bscatter<<<256, 256, 0, stream>>>(row, col, E, bstart, bcursor, pairs);
  k_bdeg<<<nbuckets, 256, 0, stream>>>(pairs, bstart, N, deg);
  k_scan_blk<<<nblk, 256, 0, stream>>>(deg, N, rowstart, blksum);
  k_scan_part<<<1, 256, 0, stream>>>(blksum, nblk, blkoff);
  k_scan_add<<<(N + 255)/256, 256, 0, stream>>>(rowstart, N, blkoff, E);
  k_bfill<<<nbuckets, 256, 0, stream>>>(pairs, bstart, rowstart, N, csrcol);

  const int gb = (N + 63) / 64;

  // ---- layer-1 QKV: Q -> Qh fp16; K -> PA slot0 (fp8, 384 B stride); V -> PB slot0 ----
  k_gemm_lds<3,0,2><<<gb, 256, 0, stream>>>(Xh, FD, Wh + 0*FD*FD,
      bq1, Qh, bk1, PA, bv1, PB, FD, REC, REC, N);

  // ---- fused: scores1 + seg_mean(x) -> SMBh + per-block softmax partials ----
  k_passA<<<nb, 256, 0, stream>>>(Qh, PA, rowstart, csrcol, scores, SMBh, 512, pm, ps, N);
  k_sm_final<<<1, 256, 0, stream>>>(pm, ps, nb, Mv, Iv);

  // s1 = relu(SMBh @ Ws1^T + bs1) -> PB slot1 (fp16, record stride 192 halfs)
  k_gemm_lds<1,1,0><<<gb, 256, 0, stream>>>(SMBh, 512, Wh + 6*FD*FD,
      bs1, (void*)((char*)PB + 128), nullptr, nullptr, nullptr, nullptr, REC/2, 0, 0, N);

  // ---- fused: message1+ELU -> Ah; seg_mean(s1) -> Bh (= SMBh region) ----
  k_passB<<<nb, 256, 0, stream>>>(PB, scores, Mv, Iv, rowstart, csrcol, Ah, SMBh, 512, N);

  // ss_out = relu(Bh @ Ws2^T + bs2) -> out cols [128,256) fp32
  k_gemm_lds<1,1,1><<<gb, 256, 0, stream>>>(SMBh, 512, Wh + 7*FD*FD,
      bs2, out + FD, nullptr, nullptr, nullptr, nullptr, 2*FD, 0, 0, N);

  // ---- layer-2 QKV: plain K8/V8 (128 B rows) ----
  k_gemm_lds<3,0,2><<<gb, 256, 0, stream>>>(Ah, FD, Wh + 3*FD*FD,
      bq2, Qh, bk2, K8, bv2, V8, FD, FD, FD, N);
  k_scores2<<<nb, 256, 0, stream>>>(Qh, K8, rowstart, csrcol, scores, pm, ps, N);
  k_sm_final<<<1, 256, 0, stream>>>(pm, ps, nb, Mv, Iv);

  // message2 -> out cols [0,128) fp32
  k_message2<<<nb, 256, 0, stream>>>(V8, scores, Mv, Iv, rowstart, csrcol, out, 2*FD, N);
}